// Round 3
// baseline (74.758 us; speedup 1.0000x reference)
//
#include <hip/hip_runtime.h>
#include <cstddef>

#define NUM_TYPE 64
#define DD 256
#define NN 8192
#define TM 16

typedef __bf16 bf16x8 __attribute__((ext_vector_type(8)));
typedef float f32x4 __attribute__((ext_vector_type(4)));

// --- Kernel 1: group samples by type (1024 thr, per-wave histograms) -----
__global__ __launch_bounds__(1024) void build_perm_kernel(
    const int* __restrict__ bi, int* __restrict__ type_off, int* __restrict__ perm) {
  __shared__ int wcnt[16][NUM_TYPE];
  __shared__ int wbase[16][NUM_TYPE];
  __shared__ int base[NUM_TYPE];
  const int tid = threadIdx.x;
  const int w = tid >> 6;
  for (int i = tid; i < 16 * NUM_TYPE; i += 1024) ((int*)wcnt)[i] = 0;
  __syncthreads();
  int myv[8];
#pragma unroll
  for (int rnd = 0; rnd < 8; ++rnd) {
    int v = bi[rnd * 1024 + tid];
    myv[rnd] = v;
    atomicAdd(&wcnt[w][v], 1);
  }
  __syncthreads();
  if (tid < NUM_TYPE) {
    int s = 0;
#pragma unroll
    for (int ww = 0; ww < 16; ++ww) { wbase[ww][tid] = s; s += wcnt[ww][tid]; }
    base[tid] = s;
  }
  __syncthreads();
  if (tid == 0) {
    int s = 0;
    for (int t = 0; t < NUM_TYPE; ++t) { int c = base[t]; base[t] = s; type_off[t] = s; s += c; }
    type_off[NUM_TYPE] = s;
  }
  __syncthreads();
  if (tid < NUM_TYPE) {
    int b = base[tid];
#pragma unroll
    for (int ww = 0; ww < 16; ++ww) wbase[ww][tid] += b;
  }
  __syncthreads();
#pragma unroll
  for (int rnd = 0; rnd < 8; ++rnd) {
    int v = myv[rnd];
    int p = atomicAdd(&wbase[w][v], 1);
    perm[p] = rnd * 1024 + tid;
  }
}

// --- helpers -------------------------------------------------------------
struct KTile {
  float4 a0, a1;          // A row fragment (8 floats)
  float4 l00, l01;        // L col cn0
  float4 l10, l11;        // L col cn1
  float4 w00, w01;        // W col cn0
  float4 w10, w11;        // W col cn1
};

__device__ __forceinline__ KTile loadk(const float* a, const float* b0, const float* b1,
                                       const float* w0, const float* w1, int ko) {
  KTile k;
  k.a0  = *reinterpret_cast<const float4*>(a + ko);
  k.a1  = *reinterpret_cast<const float4*>(a + ko + 4);
  k.l00 = *reinterpret_cast<const float4*>(b0 + ko);
  k.l01 = *reinterpret_cast<const float4*>(b0 + ko + 4);
  k.l10 = *reinterpret_cast<const float4*>(b1 + ko);
  k.l11 = *reinterpret_cast<const float4*>(b1 + ko + 4);
  k.w00 = *reinterpret_cast<const float4*>(w0 + ko);
  k.w01 = *reinterpret_cast<const float4*>(w0 + ko + 4);
  k.w10 = *reinterpret_cast<const float4*>(w1 + ko);
  k.w11 = *reinterpret_cast<const float4*>(w1 + ko + 4);
  return k;
}

__device__ __forceinline__ bf16x8 cvt2(float4 v0, float4 v1) {
  bf16x8 h;
  h[0] = (__bf16)v0.x; h[1] = (__bf16)v0.y; h[2] = (__bf16)v0.z; h[3] = (__bf16)v0.w;
  h[4] = (__bf16)v1.x; h[5] = (__bf16)v1.y; h[6] = (__bf16)v1.z; h[7] = (__bf16)v1.w;
  return h;
}

__device__ __forceinline__ float tanh_fast(float x) {
  float xc = fminf(fmaxf(x, -15.f), 15.f);
  float e = __expf(2.f * xc);
  return (e - 1.f) / (e + 1.f);
}

// --- Kernel 2: per-wave 16x32 register tile, 2-stage K pipeline ----------
__global__ __launch_bounds__(256, 4) void fused_kernel(
    const float* __restrict__ desc,    // [NN][DD]
    const float* __restrict__ layer1,  // [NUM_TYPE][DD][DD]
    const float* __restrict__ W,       // [DD][DD]
    const float* __restrict__ bias,    // [DD]
    const int* __restrict__ type_off,  // [NUM_TYPE+1]
    const int* __restrict__ perm,      // [NN]
    float* __restrict__ out) {         // [NN][DD]
  const int t = blockIdx.y;
  const int off = type_off[t];
  const int cnt = type_off[t + 1] - off;
  const int wave = threadIdx.x >> 6;
  const int lane = threadIdx.x & 63;
  const int l15 = lane & 15;
  const int lg = lane >> 4;

  const int colbase = blockIdx.x * 128 + wave * 32;
  const int cn0 = colbase + l15;
  const int cn1 = cn0 + 16;

  const float* bl0 = layer1 + ((size_t)t * DD + cn0) * DD + lg * 8;
  const float* bl1 = layer1 + ((size_t)t * DD + cn1) * DD + lg * 8;
  const float* bw0 = W + (size_t)cn0 * DD + lg * 8;
  const float* bw1 = W + (size_t)cn1 * DD + lg * 8;
  const float bv0 = bias[cn0];
  const float bv1 = bias[cn1];

  for (int mt = blockIdx.z; mt * TM < cnt; mt += 8) {
    const int r0 = mt * TM + l15;
    const int s0 = (r0 < cnt) ? perm[off + r0] : -1;
    const float* a0 = desc + (size_t)(s0 < 0 ? 0 : s0) * DD + lg * 8;

    f32x4 accL0 = {0.f, 0.f, 0.f, 0.f}, accL1 = {0.f, 0.f, 0.f, 0.f};
    f32x4 accW0 = {0.f, 0.f, 0.f, 0.f}, accW1 = {0.f, 0.f, 0.f, 0.f};

    KTile cur = loadk(a0, bl0, bl1, bw0, bw1, 0);
#pragma unroll
    for (int kc = 0; kc < 8; ++kc) {
      KTile nxt;
      if (kc < 7) nxt = loadk(a0, bl0, bl1, bw0, bw1, (kc + 1) * 32);
      bf16x8 af  = cvt2(cur.a0, cur.a1);
      bf16x8 bL0 = cvt2(cur.l00, cur.l01);
      bf16x8 bL1 = cvt2(cur.l10, cur.l11);
      bf16x8 bW0 = cvt2(cur.w00, cur.w01);
      bf16x8 bW1 = cvt2(cur.w10, cur.w11);
      accL0 = __builtin_amdgcn_mfma_f32_16x16x32_bf16(af, bL0, accL0, 0, 0, 0);
      accL1 = __builtin_amdgcn_mfma_f32_16x16x32_bf16(af, bL1, accL1, 0, 0, 0);
      accW0 = __builtin_amdgcn_mfma_f32_16x16x32_bf16(af, bW0, accW0, 0, 0, 0);
      accW1 = __builtin_amdgcn_mfma_f32_16x16x32_bf16(af, bW1, accW1, 0, 0, 0);
      cur = nxt;
    }

    // epilogue: C layout row = lg*4 + i, col = l15 (cn0) / l15+16 (cn1)
#pragma unroll
    for (int i = 0; i < 4; ++i) {
      const int sv = __shfl(s0, lg * 4 + i, 64);
      if (sv >= 0) {
        float* op = out + (size_t)sv * DD;
        op[cn0] = tanh_fast(accL0[i]) + accW0[i] + bv0;
        op[cn1] = tanh_fast(accL1[i]) + accW1[i] + bv1;
      }
    }
  }
}

extern "C" void kernel_launch(void* const* d_in, const int* in_sizes, int n_in,
                              void* d_out, int out_size, void* d_ws, size_t ws_size,
                              hipStream_t stream) {
  const int* bi       = (const int*)d_in[0];
  const float* desc   = (const float*)d_in[1];
  const float* layer1 = (const float*)d_in[2];
  const float* W      = (const float*)d_in[3];
  const float* bias   = (const float*)d_in[4];
  float* out = (float*)d_out;

  int* wsI = (int*)d_ws;
  int* type_off = wsI;        // 65 ints
  int* perm     = wsI + 72;   // 8192 ints

  hipLaunchKernelGGL(build_perm_kernel, dim3(1), dim3(1024), 0, stream, bi, type_off, perm);
  hipLaunchKernelGGL(fused_kernel, dim3(2, NUM_TYPE, 8), dim3(256), 0, stream,
                     desc, layer1, W, bias, type_off, perm, out);
}

// Round 4
// 54.460 us; speedup vs baseline: 1.3727x; 1.3727x over previous
//
#include <hip/hip_runtime.h>
#include <cstddef>

#define NUM_TYPE 64
#define DD 256
#define NN 8192

typedef __bf16 bf16x8 __attribute__((ext_vector_type(8)));
typedef float f32x4 __attribute__((ext_vector_type(4)));

// --- Kernel 1: group samples by type (1024 thr, per-wave histograms) -----
__global__ __launch_bounds__(1024) void build_perm_kernel(
    const int* __restrict__ bi, int* __restrict__ type_off, int* __restrict__ perm) {
  __shared__ int wcnt[16][NUM_TYPE];
  __shared__ int wbase[16][NUM_TYPE];
  __shared__ int base[NUM_TYPE];
  const int tid = threadIdx.x;
  const int w = tid >> 6;
  for (int i = tid; i < 16 * NUM_TYPE; i += 1024) ((int*)wcnt)[i] = 0;
  __syncthreads();
  int myv[8];
#pragma unroll
  for (int rnd = 0; rnd < 8; ++rnd) {
    int v = bi[rnd * 1024 + tid];
    myv[rnd] = v;
    atomicAdd(&wcnt[w][v], 1);
  }
  __syncthreads();
  if (tid < NUM_TYPE) {
    int s = 0;
#pragma unroll
    for (int ww = 0; ww < 16; ++ww) { wbase[ww][tid] = s; s += wcnt[ww][tid]; }
    base[tid] = s;
  }
  __syncthreads();
  if (tid == 0) {
    int s = 0;
    for (int t = 0; t < NUM_TYPE; ++t) { int c = base[t]; base[t] = s; type_off[t] = s; s += c; }
    type_off[NUM_TYPE] = s;
  }
  __syncthreads();
  if (tid < NUM_TYPE) {
    int b = base[tid];
#pragma unroll
    for (int ww = 0; ww < 16; ++ww) wbase[ww][tid] += b;
  }
  __syncthreads();
#pragma unroll
  for (int rnd = 0; rnd < 8; ++rnd) {
    int v = myv[rnd];
    int p = atomicAdd(&wbase[w][v], 1);
    perm[p] = rnd * 1024 + tid;
  }
}

// --- helpers -------------------------------------------------------------
__device__ __forceinline__ bf16x8 cvt8(const float* p) {
  float4 v0 = *reinterpret_cast<const float4*>(p);
  float4 v1 = *reinterpret_cast<const float4*>(p + 4);
  bf16x8 h;
  h[0] = (__bf16)v0.x; h[1] = (__bf16)v0.y; h[2] = (__bf16)v0.z; h[3] = (__bf16)v0.w;
  h[4] = (__bf16)v1.x; h[5] = (__bf16)v1.y; h[6] = (__bf16)v1.z; h[7] = (__bf16)v1.w;
  return h;
}

__device__ __forceinline__ float tanh_fast(float x) {
  float xc = fminf(fmaxf(x, -15.f), 15.f);
  float e = __expf(2.f * xc);
  return (e - 1.f) / (e + 1.f);
}

// --- Kernel 2: per-wave 32x32 register tile, XCD-local block placement ---
// Flat grid of 512 blocks. Block id b -> XCD b&7 (round-robin dispatch).
// All 8 blocks (2 colblocks x 4 rowslots) of type t are placed on XCD t&7,
// so L[t] (256 KB) is read into exactly one L2 and reused from there.
__global__ __launch_bounds__(256) void fused_kernel(
    const float* __restrict__ desc,    // [NN][DD]
    const float* __restrict__ layer1,  // [NUM_TYPE][DD][DD]
    const float* __restrict__ W,       // [DD][DD]
    const float* __restrict__ bias,    // [DD]
    const int* __restrict__ type_off,  // [NUM_TYPE+1]
    const int* __restrict__ perm,      // [NN]
    float* __restrict__ out) {         // [NN][DD]
  // decode XCD-aware placement
  const int bid  = blockIdx.x;
  const int xcd  = bid & 7;
  const int k    = bid >> 3;     // 0..63: k-th block on this XCD
  const int tloc = k >> 3;       // 0..7: which of this XCD's 8 types
  const int slot = k & 7;        // 0..7: 2 colblocks x 4 rowslots
  const int t    = xcd + 8 * tloc;
  const int cb   = slot & 1;
  const int zz   = slot >> 1;

  const int off = type_off[t];
  const int cnt = type_off[t + 1] - off;
  const int wave = threadIdx.x >> 6;
  const int lane = threadIdx.x & 63;
  const int l15 = lane & 15;
  const int lg = lane >> 4;

  const int colbase = cb * 128 + wave * 32;
  const int cn0 = colbase + l15;
  const int cn1 = cn0 + 16;

  const float* bl0 = layer1 + ((size_t)t * DD + cn0) * DD + lg * 8;
  const float* bl1 = layer1 + ((size_t)t * DD + cn1) * DD + lg * 8;
  const float* bw0 = W + (size_t)cn0 * DD + lg * 8;
  const float* bw1 = W + (size_t)cn1 * DD + lg * 8;
  const float bv0 = bias[cn0];
  const float bv1 = bias[cn1];

  for (int mt = zz; mt * 32 < cnt; mt += 4) {
    const int rbase = mt * 32;
    const int r0 = rbase + l15;
    const int r1 = r0 + 16;
    const int s0 = (r0 < cnt) ? perm[off + r0] : -1;
    const int s1 = (r1 < cnt) ? perm[off + r1] : -1;
    const float* a0 = desc + (size_t)(s0 < 0 ? 0 : s0) * DD + lg * 8;
    const float* a1 = desc + (size_t)(s1 < 0 ? 0 : s1) * DD + lg * 8;

    f32x4 accL[2][2] = {{{0.f,0.f,0.f,0.f},{0.f,0.f,0.f,0.f}},
                        {{0.f,0.f,0.f,0.f},{0.f,0.f,0.f,0.f}}};
    f32x4 accW[2][2] = {{{0.f,0.f,0.f,0.f},{0.f,0.f,0.f,0.f}},
                        {{0.f,0.f,0.f,0.f},{0.f,0.f,0.f,0.f}}};

#pragma unroll 2
    for (int kc = 0; kc < 8; ++kc) {
      const int ko = kc * 32;
      bf16x8 af0 = cvt8(a0 + ko);
      bf16x8 af1 = cvt8(a1 + ko);
      bf16x8 bL0 = cvt8(bl0 + ko);
      bf16x8 bL1 = cvt8(bl1 + ko);
      bf16x8 bW0 = cvt8(bw0 + ko);
      bf16x8 bW1 = cvt8(bw1 + ko);
      accL[0][0] = __builtin_amdgcn_mfma_f32_16x16x32_bf16(af0, bL0, accL[0][0], 0, 0, 0);
      accL[0][1] = __builtin_amdgcn_mfma_f32_16x16x32_bf16(af0, bL1, accL[0][1], 0, 0, 0);
      accL[1][0] = __builtin_amdgcn_mfma_f32_16x16x32_bf16(af1, bL0, accL[1][0], 0, 0, 0);
      accL[1][1] = __builtin_amdgcn_mfma_f32_16x16x32_bf16(af1, bL1, accL[1][1], 0, 0, 0);
      accW[0][0] = __builtin_amdgcn_mfma_f32_16x16x32_bf16(af0, bW0, accW[0][0], 0, 0, 0);
      accW[0][1] = __builtin_amdgcn_mfma_f32_16x16x32_bf16(af0, bW1, accW[0][1], 0, 0, 0);
      accW[1][0] = __builtin_amdgcn_mfma_f32_16x16x32_bf16(af1, bW0, accW[1][0], 0, 0, 0);
      accW[1][1] = __builtin_amdgcn_mfma_f32_16x16x32_bf16(af1, bW1, accW[1][1], 0, 0, 0);
    }

    // epilogue: C layout row = lg*4 + i (within 16), col = l15
#pragma unroll
    for (int m = 0; m < 2; ++m) {
      const int sFrag = m ? s1 : s0;
#pragma unroll
      for (int i = 0; i < 4; ++i) {
        const int sv = __shfl(sFrag, lg * 4 + i, 64);
        if (sv >= 0) {
          float* op = out + (size_t)sv * DD;
          // non-temporal: output is never re-read; keep L2 for L/W/desc panels
          __builtin_nontemporal_store(tanh_fast(accL[m][0][i]) + accW[m][0][i] + bv0, op + cn0);
          __builtin_nontemporal_store(tanh_fast(accL[m][1][i]) + accW[m][1][i] + bv1, op + cn1);
        }
      }
    }
  }
}

extern "C" void kernel_launch(void* const* d_in, const int* in_sizes, int n_in,
                              void* d_out, int out_size, void* d_ws, size_t ws_size,
                              hipStream_t stream) {
  const int* bi       = (const int*)d_in[0];
  const float* desc   = (const float*)d_in[1];
  const float* layer1 = (const float*)d_in[2];
  const float* W      = (const float*)d_in[3];
  const float* bias   = (const float*)d_in[4];
  float* out = (float*)d_out;

  int* wsI = (int*)d_ws;
  int* type_off = wsI;        // 65 ints
  int* perm     = wsI + 72;   // 8192 ints

  hipLaunchKernelGGL(build_perm_kernel, dim3(1), dim3(1024), 0, stream, bi, type_off, perm);
  hipLaunchKernelGGL(fused_kernel, dim3(512), dim3(256), 0, stream,
                     desc, layer1, W, bias, type_off, perm, out);
}

// Round 5
// 41.652 us; speedup vs baseline: 1.7948x; 1.3075x over previous
//
#include <hip/hip_runtime.h>
#include <cstddef>

#define NUM_TYPE 64
#define DD 256
#define NN 8192

typedef __bf16 bf16x8 __attribute__((ext_vector_type(8)));
typedef float f32x4 __attribute__((ext_vector_type(4)));

// --- Kernel 1: group samples by type (1024 thr, per-wave histograms) -----
__global__ __launch_bounds__(1024) void build_perm_kernel(
    const int* __restrict__ bi, int* __restrict__ type_off, int* __restrict__ perm) {
  __shared__ int wcnt[16][NUM_TYPE];
  __shared__ int wbase[16][NUM_TYPE];
  __shared__ int base[NUM_TYPE];
  const int tid = threadIdx.x;
  const int w = tid >> 6;
  for (int i = tid; i < 16 * NUM_TYPE; i += 1024) ((int*)wcnt)[i] = 0;
  __syncthreads();
  int myv[8];
#pragma unroll
  for (int rnd = 0; rnd < 8; ++rnd) {
    int v = bi[rnd * 1024 + tid];
    myv[rnd] = v;
    atomicAdd(&wcnt[w][v], 1);
  }
  __syncthreads();
  if (tid < NUM_TYPE) {
    int s = 0;
#pragma unroll
    for (int ww = 0; ww < 16; ++ww) { wbase[ww][tid] = s; s += wcnt[ww][tid]; }
    base[tid] = s;
  }
  __syncthreads();
  if (tid == 0) {
    int s = 0;
    for (int t = 0; t < NUM_TYPE; ++t) { int c = base[t]; base[t] = s; type_off[t] = s; s += c; }
    type_off[NUM_TYPE] = s;
  }
  __syncthreads();
  if (tid < NUM_TYPE) {
    int b = base[tid];
#pragma unroll
    for (int ww = 0; ww < 16; ++ww) wbase[ww][tid] += b;
  }
  __syncthreads();
#pragma unroll
  for (int rnd = 0; rnd < 8; ++rnd) {
    int v = myv[rnd];
    int p = atomicAdd(&wbase[w][v], 1);
    perm[p] = rnd * 1024 + tid;
  }
}

// --- helpers -------------------------------------------------------------
__device__ __forceinline__ bf16x8 cvt8(const float* p) {
  float4 v0 = *reinterpret_cast<const float4*>(p);
  float4 v1 = *reinterpret_cast<const float4*>(p + 4);
  bf16x8 h;
  h[0] = (__bf16)v0.x; h[1] = (__bf16)v0.y; h[2] = (__bf16)v0.z; h[3] = (__bf16)v0.w;
  h[4] = (__bf16)v1.x; h[5] = (__bf16)v1.y; h[6] = (__bf16)v1.z; h[7] = (__bf16)v1.w;
  return h;
}

__device__ __forceinline__ float tanh_fast(float x) {
  float xc = fminf(fmaxf(x, -15.f), 15.f);
  float e = __expf(2.f * xc);
  return (e - 1.f) / (e + 1.f);
}

// --- Kernel 2: B register-resident, single-burst loads, XCD-local --------
// Flat grid of 512 blocks; block id b -> XCD b&7. All 8 blocks of type t
// on XCD t&7 (L2-local L panel).
__global__ __launch_bounds__(256, 2) void fused_kernel(
    const float* __restrict__ desc,    // [NN][DD]
    const float* __restrict__ layer1,  // [NUM_TYPE][DD][DD]
    const float* __restrict__ W,       // [DD][DD]
    const float* __restrict__ bias,    // [DD]
    const int* __restrict__ type_off,  // [NUM_TYPE+1]
    const int* __restrict__ perm,      // [NN]
    float* __restrict__ out) {         // [NN][DD]
  const int bid  = blockIdx.x;
  const int xcd  = bid & 7;
  const int k    = bid >> 3;
  const int tloc = k >> 3;
  const int slot = k & 7;
  const int t    = xcd + 8 * tloc;
  const int cb   = slot & 1;
  const int zz   = slot >> 1;

  const int off = type_off[t];
  const int cnt = type_off[t + 1] - off;
  const int wave = threadIdx.x >> 6;
  const int lane = threadIdx.x & 63;
  const int l15 = lane & 15;
  const int lg = lane >> 4;

  const int colbase = cb * 128 + wave * 32;
  const int cn0 = colbase + l15;
  const int cn1 = cn0 + 16;

  const float* bl0 = layer1 + ((size_t)t * DD + cn0) * DD + lg * 8;
  const float* bl1 = layer1 + ((size_t)t * DD + cn1) * DD + lg * 8;
  const float* bw0 = W + (size_t)cn0 * DD + lg * 8;
  const float* bw1 = W + (size_t)cn1 * DD + lg * 8;
  const float bv0 = bias[cn0];
  const float bv1 = bias[cn1];

  // ---- hoist B into registers: 8 chunks x 4 fragments (128 VGPRs bf16) --
  bf16x8 Bl0[8], Bl1[8], Bw0[8], Bw1[8];
#pragma unroll
  for (int kc = 0; kc < 8; ++kc) {
    Bl0[kc] = cvt8(bl0 + kc * 32);
    Bl1[kc] = cvt8(bl1 + kc * 32);
    Bw0[kc] = cvt8(bw0 + kc * 32);
    Bw1[kc] = cvt8(bw1 + kc * 32);
  }

  for (int mt = zz; mt * 32 < cnt; mt += 4) {
    const int r0 = mt * 32 + l15;
    const int r1 = r0 + 16;
    const int s0 = (r0 < cnt) ? perm[off + r0] : -1;
    const int s1 = (r1 < cnt) ? perm[off + r1] : -1;
    const float* a0 = desc + (size_t)(s0 < 0 ? 0 : s0) * DD + lg * 8;
    const float* a1 = desc + (size_t)(s1 < 0 ? 0 : s1) * DD + lg * 8;

    // ---- A tile: one burst of 16 loads, cvt to 64 bf16 regs -------------
    bf16x8 Af0[8], Af1[8];
#pragma unroll
    for (int kc = 0; kc < 8; ++kc) {
      Af0[kc] = cvt8(a0 + kc * 32);
      Af1[kc] = cvt8(a1 + kc * 32);
    }

    f32x4 accL[2][2] = {{{0.f,0.f,0.f,0.f},{0.f,0.f,0.f,0.f}},
                        {{0.f,0.f,0.f,0.f},{0.f,0.f,0.f,0.f}}};
    f32x4 accW[2][2] = {{{0.f,0.f,0.f,0.f},{0.f,0.f,0.f,0.f}},
                        {{0.f,0.f,0.f,0.f},{0.f,0.f,0.f,0.f}}};
#pragma unroll
    for (int kc = 0; kc < 8; ++kc) {
      accL[0][0] = __builtin_amdgcn_mfma_f32_16x16x32_bf16(Af0[kc], Bl0[kc], accL[0][0], 0, 0, 0);
      accL[0][1] = __builtin_amdgcn_mfma_f32_16x16x32_bf16(Af0[kc], Bl1[kc], accL[0][1], 0, 0, 0);
      accL[1][0] = __builtin_amdgcn_mfma_f32_16x16x32_bf16(Af1[kc], Bl0[kc], accL[1][0], 0, 0, 0);
      accL[1][1] = __builtin_amdgcn_mfma_f32_16x16x32_bf16(Af1[kc], Bl1[kc], accL[1][1], 0, 0, 0);
      accW[0][0] = __builtin_amdgcn_mfma_f32_16x16x32_bf16(Af0[kc], Bw0[kc], accW[0][0], 0, 0, 0);
      accW[0][1] = __builtin_amdgcn_mfma_f32_16x16x32_bf16(Af0[kc], Bw1[kc], accW[0][1], 0, 0, 0);
      accW[1][0] = __builtin_amdgcn_mfma_f32_16x16x32_bf16(Af1[kc], Bw0[kc], accW[1][0], 0, 0, 0);
      accW[1][1] = __builtin_amdgcn_mfma_f32_16x16x32_bf16(Af1[kc], Bw1[kc], accW[1][1], 0, 0, 0);
    }

    // epilogue: C layout row = lg*4 + i (within 16), col = l15
#pragma unroll
    for (int m = 0; m < 2; ++m) {
      const int sFrag = m ? s1 : s0;
#pragma unroll
      for (int i = 0; i < 4; ++i) {
        const int sv = __shfl(sFrag, lg * 4 + i, 64);
        if (sv >= 0) {
          float* op = out + (size_t)sv * DD;
          __builtin_nontemporal_store(tanh_fast(accL[m][0][i]) + accW[m][0][i] + bv0, op + cn0);
          __builtin_nontemporal_store(tanh_fast(accL[m][1][i]) + accW[m][1][i] + bv1, op + cn1);
        }
      }
    }
  }
}

extern "C" void kernel_launch(void* const* d_in, const int* in_sizes, int n_in,
                              void* d_out, int out_size, void* d_ws, size_t ws_size,
                              hipStream_t stream) {
  const int* bi       = (const int*)d_in[0];
  const float* desc   = (const float*)d_in[1];
  const float* layer1 = (const float*)d_in[2];
  const float* W      = (const float*)d_in[3];
  const float* bias   = (const float*)d_in[4];
  float* out = (float*)d_out;

  int* wsI = (int*)d_ws;
  int* type_off = wsI;        // 65 ints
  int* perm     = wsI + 72;   // 8192 ints

  hipLaunchKernelGGL(build_perm_kernel, dim3(1), dim3(1024), 0, stream, bi, type_off, perm);
  hipLaunchKernelGGL(fused_kernel, dim3(512), dim3(256), 0, stream,
                     desc, layer1, W, bias, type_off, perm, out);
}

// Round 7
// 37.995 us; speedup vs baseline: 1.9676x; 1.0963x over previous
//
#include <hip/hip_runtime.h>
#include <cstddef>

#define NUM_TYPE 64
#define DD 256
#define NN 8192

typedef __bf16 bf16x8 __attribute__((ext_vector_type(8)));
typedef __bf16 bf16x4 __attribute__((ext_vector_type(4)));
typedef float f32x4 __attribute__((ext_vector_type(4)));

__device__ __forceinline__ void cvtstore4(const float4 v, __bf16* dst) {
  bf16x4 h;
  h[0] = (__bf16)v.x; h[1] = (__bf16)v.y; h[2] = (__bf16)v.z; h[3] = (__bf16)v.w;
  *reinterpret_cast<bf16x4*>(dst) = h;
}

__device__ __forceinline__ bf16x8 cvt8(const float* p) {
  float4 v0 = *reinterpret_cast<const float4*>(p);
  float4 v1 = *reinterpret_cast<const float4*>(p + 4);
  bf16x8 h;
  h[0] = (__bf16)v0.x; h[1] = (__bf16)v0.y; h[2] = (__bf16)v0.z; h[3] = (__bf16)v0.w;
  h[4] = (__bf16)v1.x; h[5] = (__bf16)v1.y; h[6] = (__bf16)v1.z; h[7] = (__bf16)v1.w;
  return h;
}

__device__ __forceinline__ float tanh_fast(float x) {
  float xc = fminf(fmaxf(x, -15.f), 15.f);
  float e = __expf(2.f * xc);
  return (e - 1.f) / (e + 1.f);
}

// --- Kernel 1: prep = bf16 conversion (blocks 0..511) + perm (block 512) -
// layer1 per type = 65536 floats = 16384 float4; per part (of 8) = 2048 f4.
__global__ __launch_bounds__(256) void prep_kernel(
    const int* __restrict__ bi,
    const float* __restrict__ desc,
    const float* __restrict__ layer1,
    const float* __restrict__ W,
    int* __restrict__ type_off,
    int* __restrict__ perm,
    __bf16* __restrict__ Lb,
    __bf16* __restrict__ Db,
    __bf16* __restrict__ Wb) {
  const int bid = blockIdx.x;
  const int tid = threadIdx.x;

  if (bid == 512) {
    __shared__ int wcnt[4][NUM_TYPE];
    __shared__ int wbase[4][NUM_TYPE];
    __shared__ int tstart[NUM_TYPE];
    const int w = tid >> 6;
    ((int*)wcnt)[tid] = 0;               // 4*64 == 256
    __syncthreads();
#pragma unroll
    for (int r = 0; r < 32; ++r) {
      int v = bi[r * 256 + tid];
      atomicAdd(&wcnt[w][v], 1);
    }
    __syncthreads();
    if (tid < NUM_TYPE) {
      int s = 0;
#pragma unroll
      for (int ww = 0; ww < 4; ++ww) { wbase[ww][tid] = s; s += wcnt[ww][tid]; }
      wcnt[0][tid] = s;                  // per-type total
    }
    __syncthreads();
    if (tid == 0) {
      int s = 0;
      for (int t = 0; t < NUM_TYPE; ++t) {
        int c = wcnt[0][t];
        tstart[t] = s; type_off[t] = s; s += c;
      }
      type_off[NUM_TYPE] = s;
    }
    __syncthreads();
    if (tid < NUM_TYPE) {
      int b = tstart[tid];
#pragma unroll
      for (int ww = 0; ww < 4; ++ww) wbase[ww][tid] += b;
    }
    __syncthreads();
#pragma unroll
    for (int r = 0; r < 32; ++r) {
      int i = r * 256 + tid;
      int v = bi[i];
      int p = atomicAdd(&wbase[w][v], 1);
      perm[p] = i;
    }
    return;
  }

  // ---- conversion blocks 0..511: one (type, part) L slice each ----
  const int xcd  = bid & 7;
  const int jj   = bid >> 3;      // 0..63
  const int tloc = jj >> 3;       // 0..7
  const int part = jj & 7;        // 0..7
  const int t    = xcd + 8 * tloc;
  {
    const size_t baseF4 = (size_t)t * 16384 + (size_t)part * 2048;  // float4 units
    const float4* src = reinterpret_cast<const float4*>(layer1) + baseF4;
    __bf16* dst = Lb + baseF4 * 4;
#pragma unroll
    for (int i = tid; i < 2048; i += 256)
      cvtstore4(src[i], dst + (size_t)i * 4);
  }
  // desc (524288 f4) + W (16384 f4) strided across the 512 conv blocks
  {
    const float4* srcD = reinterpret_cast<const float4*>(desc);
    const float4* srcW = reinterpret_cast<const float4*>(W);
    for (size_t i = (size_t)bid * 256 + tid; i < 540672; i += 512 * 256) {
      if (i < 524288) cvtstore4(srcD[i], Db + i * 4);
      else            cvtstore4(srcW[i - 524288], Wb + (i - 524288) * 4);
    }
  }
}

// --- Kernel 2: bf16 GEMM, register tiles, XCD-local placement ------------
__global__ __launch_bounds__(256, 2) void fused_kernel_bf16(
    const __bf16* __restrict__ Db,
    const __bf16* __restrict__ Lb,
    const __bf16* __restrict__ Wb,
    const float* __restrict__ bias,
    const int* __restrict__ type_off,
    const int* __restrict__ perm,
    float* __restrict__ out) {
  const int bid  = blockIdx.x;
  const int xcd  = bid & 7;
  const int k    = bid >> 3;
  const int tloc = k >> 3;
  const int slot = k & 7;
  const int t    = xcd + 8 * tloc;
  const int cb   = slot & 1;
  const int zz   = slot >> 1;

  const int off = type_off[t];
  const int cnt = type_off[t + 1] - off;
  const int wave = threadIdx.x >> 6;
  const int lane = threadIdx.x & 63;
  const int l15 = lane & 15;
  const int lg = lane >> 4;

  const int colbase = cb * 128 + wave * 32;
  const int cn0 = colbase + l15;
  const int cn1 = cn0 + 16;

  const __bf16* bl0 = Lb + ((size_t)t * DD + cn0) * DD + lg * 8;
  const __bf16* bl1 = Lb + ((size_t)t * DD + cn1) * DD + lg * 8;
  const __bf16* bw0 = Wb + (size_t)cn0 * DD + lg * 8;
  const __bf16* bw1 = Wb + (size_t)cn1 * DD + lg * 8;
  const float bv0 = bias[cn0];
  const float bv1 = bias[cn1];

  for (int mt = zz; mt * 32 < cnt; mt += 4) {
    const int r0 = mt * 32 + l15;
    const int r1 = r0 + 16;
    const int s0 = (r0 < cnt) ? perm[off + r0] : -1;
    const int s1 = (r1 < cnt) ? perm[off + r1] : -1;
    const __bf16* a0 = Db + (size_t)(s0 < 0 ? 0 : s0) * DD + lg * 8;
    const __bf16* a1 = Db + (size_t)(s1 < 0 ? 0 : s1) * DD + lg * 8;

    f32x4 accL[2][2] = {{{0.f,0.f,0.f,0.f},{0.f,0.f,0.f,0.f}},
                        {{0.f,0.f,0.f,0.f},{0.f,0.f,0.f,0.f}}};
    f32x4 accW[2][2] = {{{0.f,0.f,0.f,0.f},{0.f,0.f,0.f,0.f}},
                        {{0.f,0.f,0.f,0.f},{0.f,0.f,0.f,0.f}}};

#pragma unroll
    for (int kc = 0; kc < 8; ++kc) {
      const int ko = kc * 32;
      bf16x8 af0 = *reinterpret_cast<const bf16x8*>(a0 + ko);
      bf16x8 af1 = *reinterpret_cast<const bf16x8*>(a1 + ko);
      bf16x8 bL0 = *reinterpret_cast<const bf16x8*>(bl0 + ko);
      bf16x8 bL1 = *reinterpret_cast<const bf16x8*>(bl1 + ko);
      bf16x8 bW0 = *reinterpret_cast<const bf16x8*>(bw0 + ko);
      bf16x8 bW1 = *reinterpret_cast<const bf16x8*>(bw1 + ko);
      accL[0][0] = __builtin_amdgcn_mfma_f32_16x16x32_bf16(af0, bL0, accL[0][0], 0, 0, 0);
      accL[0][1] = __builtin_amdgcn_mfma_f32_16x16x32_bf16(af0, bL1, accL[0][1], 0, 0, 0);
      accL[1][0] = __builtin_amdgcn_mfma_f32_16x16x32_bf16(af1, bL0, accL[1][0], 0, 0, 0);
      accL[1][1] = __builtin_amdgcn_mfma_f32_16x16x32_bf16(af1, bL1, accL[1][1], 0, 0, 0);
      accW[0][0] = __builtin_amdgcn_mfma_f32_16x16x32_bf16(af0, bW0, accW[0][0], 0, 0, 0);
      accW[0][1] = __builtin_amdgcn_mfma_f32_16x16x32_bf16(af0, bW1, accW[0][1], 0, 0, 0);
      accW[1][0] = __builtin_amdgcn_mfma_f32_16x16x32_bf16(af1, bW0, accW[1][0], 0, 0, 0);
      accW[1][1] = __builtin_amdgcn_mfma_f32_16x16x32_bf16(af1, bW1, accW[1][1], 0, 0, 0);
    }

#pragma unroll
    for (int m = 0; m < 2; ++m) {
      const int sFrag = m ? s1 : s0;
#pragma unroll
      for (int i = 0; i < 4; ++i) {
        const int sv = __shfl(sFrag, lg * 4 + i, 64);
        if (sv >= 0) {
          float* op = out + (size_t)sv * DD;
          __builtin_nontemporal_store(tanh_fast(accL[m][0][i]) + accW[m][0][i] + bv0, op + cn0);
          __builtin_nontemporal_store(tanh_fast(accL[m][1][i]) + accW[m][1][i] + bv1, op + cn1);
        }
      }
    }
  }
}

// --- Fallback (round-5 proven): fp32 loads, B hoisted, inline cvt --------
__global__ __launch_bounds__(1024) void build_perm_kernel(
    const int* __restrict__ bi, int* __restrict__ type_off, int* __restrict__ perm) {
  __shared__ int wcnt[16][NUM_TYPE];
  __shared__ int wbase[16][NUM_TYPE];
  __shared__ int base[NUM_TYPE];
  const int tid = threadIdx.x;
  const int w = tid >> 6;
  for (int i = tid; i < 16 * NUM_TYPE; i += 1024) ((int*)wcnt)[i] = 0;
  __syncthreads();
  int myv[8];
#pragma unroll
  for (int rnd = 0; rnd < 8; ++rnd) {
    int v = bi[rnd * 1024 + tid];
    myv[rnd] = v;
    atomicAdd(&wcnt[w][v], 1);
  }
  __syncthreads();
  if (tid < NUM_TYPE) {
    int s = 0;
#pragma unroll
    for (int ww = 0; ww < 16; ++ww) { wbase[ww][tid] = s; s += wcnt[ww][tid]; }
    base[tid] = s;
  }
  __syncthreads();
  if (tid == 0) {
    int s = 0;
    for (int t = 0; t < NUM_TYPE; ++t) { int c = base[t]; base[t] = s; type_off[t] = s; s += c; }
    type_off[NUM_TYPE] = s;
  }
  __syncthreads();
  if (tid < NUM_TYPE) {
    int b = base[tid];
#pragma unroll
    for (int ww = 0; ww < 16; ++ww) wbase[ww][tid] += b;
  }
  __syncthreads();
#pragma unroll
  for (int rnd = 0; rnd < 8; ++rnd) {
    int v = myv[rnd];
    int p = atomicAdd(&wbase[w][v], 1);
    perm[p] = rnd * 1024 + tid;
  }
}

__global__ __launch_bounds__(256, 2) void fused_kernel_f32(
    const float* __restrict__ desc,
    const float* __restrict__ layer1,
    const float* __restrict__ W,
    const float* __restrict__ bias,
    const int* __restrict__ type_off,
    const int* __restrict__ perm,
    float* __restrict__ out) {
  const int bid  = blockIdx.x;
  const int xcd  = bid & 7;
  const int k    = bid >> 3;
  const int tloc = k >> 3;
  const int slot = k & 7;
  const int t    = xcd + 8 * tloc;
  const int cb   = slot & 1;
  const int zz   = slot >> 1;

  const int off = type_off[t];
  const int cnt = type_off[t + 1] - off;
  const int wave = threadIdx.x >> 6;
  const int lane = threadIdx.x & 63;
  const int l15 = lane & 15;
  const int lg = lane >> 4;

  const int colbase = cb * 128 + wave * 32;
  const int cn0 = colbase + l15;
  const int cn1 = cn0 + 16;

  const float* bl0 = layer1 + ((size_t)t * DD + cn0) * DD + lg * 8;
  const float* bl1 = layer1 + ((size_t)t * DD + cn1) * DD + lg * 8;
  const float* bw0 = W + (size_t)cn0 * DD + lg * 8;
  const float* bw1 = W + (size_t)cn1 * DD + lg * 8;
  const float bv0 = bias[cn0];
  const float bv1 = bias[cn1];

  bf16x8 Bl0[8], Bl1[8], Bw0[8], Bw1[8];
#pragma unroll
  for (int kc = 0; kc < 8; ++kc) {
    Bl0[kc] = cvt8(bl0 + kc * 32);
    Bl1[kc] = cvt8(bl1 + kc * 32);
    Bw0[kc] = cvt8(bw0 + kc * 32);
    Bw1[kc] = cvt8(bw1 + kc * 32);
  }

  for (int mt = zz; mt * 32 < cnt; mt += 4) {
    const int r0 = mt * 32 + l15;
    const int r1 = r0 + 16;
    const int s0 = (r0 < cnt) ? perm[off + r0] : -1;
    const int s1 = (r1 < cnt) ? perm[off + r1] : -1;
    const float* a0 = desc + (size_t)(s0 < 0 ? 0 : s0) * DD + lg * 8;
    const float* a1 = desc + (size_t)(s1 < 0 ? 0 : s1) * DD + lg * 8;

    bf16x8 Af0[8], Af1[8];
#pragma unroll
    for (int kc = 0; kc < 8; ++kc) {
      Af0[kc] = cvt8(a0 + kc * 32);
      Af1[kc] = cvt8(a1 + kc * 32);
    }

    f32x4 accL[2][2] = {{{0.f,0.f,0.f,0.f},{0.f,0.f,0.f,0.f}},
                        {{0.f,0.f,0.f,0.f},{0.f,0.f,0.f,0.f}}};
    f32x4 accW[2][2] = {{{0.f,0.f,0.f,0.f},{0.f,0.f,0.f,0.f}},
                        {{0.f,0.f,0.f,0.f},{0.f,0.f,0.f,0.f}}};
#pragma unroll
    for (int kc = 0; kc < 8; ++kc) {
      accL[0][0] = __builtin_amdgcn_mfma_f32_16x16x32_bf16(Af0[kc], Bl0[kc], accL[0][0], 0, 0, 0);
      accL[0][1] = __builtin_amdgcn_mfma_f32_16x16x32_bf16(Af0[kc], Bl1[kc], accL[0][1], 0, 0, 0);
      accL[1][0] = __builtin_amdgcn_mfma_f32_16x16x32_bf16(Af1[kc], Bl0[kc], accL[1][0], 0, 0, 0);
      accL[1][1] = __builtin_amdgcn_mfma_f32_16x16x32_bf16(Af1[kc], Bl1[kc], accL[1][1], 0, 0, 0);
      accW[0][0] = __builtin_amdgcn_mfma_f32_16x16x32_bf16(Af0[kc], Bw0[kc], accW[0][0], 0, 0, 0);
      accW[0][1] = __builtin_amdgcn_mfma_f32_16x16x32_bf16(Af0[kc], Bw1[kc], accW[0][1], 0, 0, 0);
      accW[1][0] = __builtin_amdgcn_mfma_f32_16x16x32_bf16(Af1[kc], Bw0[kc], accW[1][0], 0, 0, 0);
      accW[1][1] = __builtin_amdgcn_mfma_f32_16x16x32_bf16(Af1[kc], Bw1[kc], accW[1][1], 0, 0, 0);
    }

#pragma unroll
    for (int m = 0; m < 2; ++m) {
      const int sFrag = m ? s1 : s0;
#pragma unroll
      for (int i = 0; i < 4; ++i) {
        const int sv = __shfl(sFrag, lg * 4 + i, 64);
        if (sv >= 0) {
          float* op = out + (size_t)sv * DD;
          __builtin_nontemporal_store(tanh_fast(accL[m][0][i]) + accW[m][0][i] + bv0, op + cn0);
          __builtin_nontemporal_store(tanh_fast(accL[m][1][i]) + accW[m][1][i] + bv1, op + cn1);
        }
      }
    }
  }
}

extern "C" void kernel_launch(void* const* d_in, const int* in_sizes, int n_in,
                              void* d_out, int out_size, void* d_ws, size_t ws_size,
                              hipStream_t stream) {
  const int* bi       = (const int*)d_in[0];
  const float* desc   = (const float*)d_in[1];
  const float* layer1 = (const float*)d_in[2];
  const float* W      = (const float*)d_in[3];
  const float* bias   = (const float*)d_in[4];
  float* out = (float*)d_out;

  char* ws = (char*)d_ws;
  int* type_off = (int*)(ws);                          // 65 ints  @ 0
  int* perm     = (int*)(ws + 1024);                   // 8192 ints @ 1 KB
  __bf16* Lb    = (__bf16*)(ws + 65536);               // 8 MB     @ 64 KB
  __bf16* Db    = (__bf16*)(ws + 65536 + 8388608);     // 4 MB
  __bf16* Wb    = (__bf16*)(ws + 65536 + 8388608 + 4194304); // 128 KB
  const size_t NEED = 65536 + 8388608 + 4194304 + 131072;

  if (ws_size >= NEED) {
    hipLaunchKernelGGL(prep_kernel, dim3(513), dim3(256), 0, stream,
                       bi, desc, layer1, W, type_off, perm, Lb, Db, Wb);
    hipLaunchKernelGGL(fused_kernel_bf16, dim3(512), dim3(256), 0, stream,
                       Db, Lb, Wb, bias, type_off, perm, out);
  } else {
    hipLaunchKernelGGL(build_perm_kernel, dim3(1), dim3(1024), 0, stream,
                       bi, type_off, perm);
    hipLaunchKernelGGL(fused_kernel_f32, dim3(512), dim3(256), 0, stream,
                       desc, layer1, W, bias, type_off, perm, out);
  }
}